// Round 1
// baseline (58.246 us; speedup 1.0000x reference)
//
#include <hip/hip_runtime.h>
#include <math.h>

#define BATCH 8
#define NN 2048
#define DD 128

// Kernel 1: per-row dual dot products. One 64-lane wave per row (B*N rows).
__global__ __launch_bounds__(256) void score_kernel(
    const float* __restrict__ x, const float* __restrict__ W,
    const float* __restrict__ bias,
    float* __restrict__ sl, float* __restrict__ sr) {
    int wave = (blockIdx.x * blockDim.x + threadIdx.x) >> 6;
    int lane = threadIdx.x & 63;
    if (wave >= BATCH * NN) return;
    const float* xr = x + (size_t)wave * DD;
    float x0 = xr[lane];
    float x1 = xr[lane + 64];
    float l = x0 * W[lane] + x1 * W[lane + 64];
    float r = x0 * W[DD + lane] + x1 * W[DD + lane + 64];
    #pragma unroll
    for (int off = 32; off; off >>= 1) {
        l += __shfl_xor(l, off, 64);
        r += __shfl_xor(r, off, 64);
    }
    if (lane == 0) {
        sl[wave] = l + bias[0];
        sr[wave] = r;
    }
}

// Kernel 2: out[b,i,j] = adj[b,i,j] * sigmoid(sl[b,i] + sr[b,j])
// Vectorized float4, grid-stride. N=2048 -> 512 float4 per row, so each
// wave sits entirely inside one row (sl is wave-uniform).
__global__ __launch_bounds__(256) void att_kernel(
    const float* __restrict__ adj, const float* __restrict__ sl,
    const float* __restrict__ sr, float* __restrict__ out) {
    const long total = (long)BATCH * NN * (NN / 4);   // 8.4M float4
    long stride = (long)gridDim.x * blockDim.x;
    for (long e = (long)blockIdx.x * blockDim.x + threadIdx.x; e < total; e += stride) {
        long row = e >> 9;                 // / 512
        int j4 = ((int)e & 511) << 2;      // column start (elements)
        int b  = (int)(row >> 11);         // / 2048
        float slv = sl[row];
        const float4 s4 = *(const float4*)(sr + (size_t)b * NN + j4);
        const float4 a  = *(const float4*)(adj + ((size_t)row * NN + j4));
        float4 o;
        o.x = a.x / (1.0f + __expf(-(slv + s4.x)));
        o.y = a.y / (1.0f + __expf(-(slv + s4.y)));
        o.z = a.z / (1.0f + __expf(-(slv + s4.z)));
        o.w = a.w / (1.0f + __expf(-(slv + s4.w)));
        *(float4*)(out + ((size_t)row * NN + j4)) = o;
    }
}

extern "C" void kernel_launch(void* const* d_in, const int* in_sizes, int n_in,
                              void* d_out, int out_size, void* d_ws, size_t ws_size,
                              hipStream_t stream) {
    const float* x   = (const float*)d_in[0];   // (8,2048,128)
    const float* adj = (const float*)d_in[1];   // (8,2048,2048)
    const float* W   = (const float*)d_in[2];   // (256,)
    const float* b   = (const float*)d_in[3];   // (1,)
    float* out = (float*)d_out;

    float* sl = (float*)d_ws;                   // 16384 floats
    float* sr = sl + BATCH * NN;                // 16384 floats

    // Kernel 1: 16384 waves, 4 waves/block
    int rows = BATCH * NN;
    int blocks1 = rows / 4;                     // 4096
    score_kernel<<<blocks1, 256, 0, stream>>>(x, W, b, sl, sr);

    // Kernel 2: grid-stride over 8.4M float4
    int blocks2 = 2048;
    att_kernel<<<blocks2, 256, 0, stream>>>(adj, sl, sr, out);
}

// Round 3
// 55.331 us; speedup vs baseline: 1.0527x; 1.0527x over previous
//
#include <hip/hip_runtime.h>
#include <math.h>

#define BATCH 8
#define NN 2048
#define DD 128

typedef float vf4 __attribute__((ext_vector_type(4)));

// Kernel 1: per-row dual dot products. One 64-lane wave per row (B*N rows).
__global__ __launch_bounds__(256) void score_kernel(
    const float* __restrict__ x, const float* __restrict__ W,
    const float* __restrict__ bias,
    float* __restrict__ sl, float* __restrict__ sr) {
    int wave = (blockIdx.x * blockDim.x + threadIdx.x) >> 6;
    int lane = threadIdx.x & 63;
    if (wave >= BATCH * NN) return;
    const float* xr = x + (size_t)wave * DD;
    float x0 = xr[lane];
    float x1 = xr[lane + 64];
    float l = x0 * W[lane] + x1 * W[lane + 64];
    float r = x0 * W[DD + lane] + x1 * W[DD + lane + 64];
    #pragma unroll
    for (int off = 32; off; off >>= 1) {
        l += __shfl_xor(l, off, 64);
        r += __shfl_xor(r, off, 64);
    }
    if (lane == 0) {
        sl[wave] = l + bias[0];
        sr[wave] = r;
    }
}

// Kernel 2: out[b,i,j] = adj[b,i,j] * sigmoid(sl[b,i] + sr[b,j])
// Static mapping: block k owns rows [8k, 8k+8); each row = 512 float4,
// covered by 256 threads x 2. sl is wave-uniform (scalar load path);
// adj/out are streamed nontemporal; sr (64 KB) stays cache-hot.
__global__ __launch_bounds__(256) void att_kernel(
    const float* __restrict__ adj, const float* __restrict__ sl,
    const float* __restrict__ sr, float* __restrict__ out) {
    const int row0 = blockIdx.x * 8;
    const int b = row0 >> 11;                    // batch (8 rows never straddle)
    const vf4* srb = (const vf4*)(sr + (size_t)b * NN);
    const int tid = threadIdx.x;
    #pragma unroll
    for (int r = 0; r < 8; ++r) {
        const size_t row = row0 + r;
        const float slv = sl[row];
        const vf4* arow = (const vf4*)(adj + row * NN);
        vf4* orow = (vf4*)(out + row * NN);
        #pragma unroll
        for (int h = 0; h < 2; ++h) {
            const int j4 = h * 256 + tid;
            const vf4 s4 = srb[j4];
            const vf4 a = __builtin_nontemporal_load(arow + j4);
            vf4 o;
            o.x = a.x * __builtin_amdgcn_rcpf(1.0f + __expf(-(slv + s4.x)));
            o.y = a.y * __builtin_amdgcn_rcpf(1.0f + __expf(-(slv + s4.y)));
            o.z = a.z * __builtin_amdgcn_rcpf(1.0f + __expf(-(slv + s4.z)));
            o.w = a.w * __builtin_amdgcn_rcpf(1.0f + __expf(-(slv + s4.w)));
            __builtin_nontemporal_store(o, orow + j4);
        }
    }
}

extern "C" void kernel_launch(void* const* d_in, const int* in_sizes, int n_in,
                              void* d_out, int out_size, void* d_ws, size_t ws_size,
                              hipStream_t stream) {
    const float* x   = (const float*)d_in[0];   // (8,2048,128)
    const float* adj = (const float*)d_in[1];   // (8,2048,2048)
    const float* W   = (const float*)d_in[2];   // (256,)
    const float* b   = (const float*)d_in[3];   // (1,)
    float* out = (float*)d_out;

    float* sl = (float*)d_ws;                   // 16384 floats
    float* sr = sl + BATCH * NN;                // 16384 floats

    // Kernel 1: 16384 waves, one per row
    int rows = BATCH * NN;
    int blocks1 = rows / 4;                     // 4096 blocks x 4 waves
    score_kernel<<<blocks1, 256, 0, stream>>>(x, W, b, sl, sr);

    // Kernel 2: 2048 blocks x 8 rows each (exact cover of 16384 rows)
    att_kernel<<<BATCH * NN / 8, 256, 0, stream>>>(adj, sl, sr, out);
}